// Round 4
// baseline (400.160 us; speedup 1.0000x reference)
//
#include <hip/hip_runtime.h>
#include <hip/hip_fp8.h>
#include <stdint.h>

#define K_DIM 4096
#define N_DIM 4096
#define NKB   32     // number of 128-wide K scale blocks

using f32x4 = __attribute__((ext_vector_type(4))) float;
using i32x4 = __attribute__((ext_vector_type(4))) int;
using i32x8 = __attribute__((ext_vector_type(8))) int;

#define GLOAD_LDS16(g, l)                                                      \
    __builtin_amdgcn_global_load_lds(                                          \
        (const __attribute__((address_space(1))) unsigned int*)(g),            \
        (__attribute__((address_space(3))) unsigned int*)(l), 16, 0, 0)
#define GLOAD_LDS4(g, l)                                                       \
    __builtin_amdgcn_global_load_lds(                                          \
        (const __attribute__((address_space(1))) unsigned int*)(g),            \
        (__attribute__((address_space(3))) unsigned int*)(l), 4, 0, 0)

__device__ __forceinline__ uint8_t to_fp8(float v) {
    __hip_fp8_e4m3 q(v);   // OCP e4m3fn, RNE saturating
    return (uint8_t)q.__x;
}

// ---------------- activation quant: one wave per (m, kb); scales TRANSPOSED saT[kb][m] ----------------
__global__ __launch_bounds__(256) void act_quant_kernel(
    const float* __restrict__ x, uint8_t* __restrict__ xq,
    float* __restrict__ saT, int M)
{
    int gw   = blockIdx.x * 4 + (threadIdx.x >> 6);
    int lane = threadIdx.x & 63;
    int m    = gw >> 5;
    int kb   = gw & 31;
    size_t base = (size_t)m * K_DIM + kb * 128 + lane * 2;
    float2 v = *(const float2*)(x + base);
    float amax = fmaxf(fabsf(v.x), fabsf(v.y));
    #pragma unroll
    for (int o = 32; o >= 1; o >>= 1) amax = fmaxf(amax, __shfl_xor(amax, o));
    float s = amax / 448.0f;          // IEEE div, matches jnp exactly
    uchar2 q;
    q.x = to_fp8(v.x / s);
    q.y = to_fp8(v.y / s);
    *(uchar2*)(xq + base) = q;
    if (lane == 0) saT[(size_t)kb * M + m] = s;
}

// ---------------- weight quant ----------------
__global__ __launch_bounds__(256) void w_quant_kernel(
    const float* __restrict__ w, uint8_t* __restrict__ wq)
{
    size_t i = ((size_t)blockIdx.x * 256 + threadIdx.x) * 4;
    float4 v = *(const float4*)(w + i);
    uchar4 q;
    q.x = to_fp8(v.x); q.y = to_fp8(v.y); q.z = to_fp8(v.z); q.w = to_fp8(v.w);
    *(uchar4*)(wq + i) = q;
}

// ---------------- MX fp8 GEMM, 256x256 tile, BK=128, 4-phase pipelined ----------------
// LDS: buf0 A|B 64KB, buf1 A|B 64KB, scale rows 2x1KB = 133120 B
#define LS_A(b) ((b) * 65536)
#define LS_B(b) ((b) * 65536 + 32768)
#define LS_S(b) (131072 + (b) * 1024)

__global__ __launch_bounds__(512, 2) void fp8_gemm_mx2(
    const uint8_t* __restrict__ Aq, const uint8_t* __restrict__ Bq,
    const float* __restrict__ saT, const float* __restrict__ wscale,
    float* __restrict__ C, int M)
{
    __shared__ __align__(16) uint8_t lds[133120];

    const int t    = threadIdx.x;
    const int lane = t & 63;
    const int lr   = lane & 15;
    const int lk   = lane >> 4;
    const int wid  = t >> 6;
    const int wm   = wid >> 2;          // 0..1
    const int wn   = wid & 3;           // 0..3

    const int gridN = N_DIM / 256;      // 16
    int nwg = (M / 256) * gridN;        // 512, %8==0
    int cpx = nwg >> 3;
    int bid = blockIdx.x;
    int swz = (bid & 7) * cpx + (bid >> 3);   // bijective XCD swizzle
    const int m0 = (swz / gridN) * 256;
    const int n0 = (swz % gridN) * 256;
    const int nbI = ((n0 >> 7) + (wn >> 1)) * NKB;  // wscale row base for this wave

    // staging map: thread -> (row srow, phys chunk t&7); source logical chunk
    // ((t&7)^(srow&7)) so that phys_chunk = logical_chunk ^ (row&7) in LDS.
    const int srow = t >> 3;                        // 0..63 per pass
    const int scol = ((t & 7) ^ (srow & 7)) * 16;
    const uint8_t* gA = Aq + (size_t)(m0 + srow) * K_DIM + scol;
    const uint8_t* gB = Bq + (size_t)(n0 + srow) * K_DIM + scol;
    const int dst = t * 16;                         // 8KB per pass

    const int fsw = (lr & 7) << 4;                  // fragment read swizzle

    f32x4 acc[8][4] = {};
    const f32x4 vzero = {0.f, 0.f, 0.f, 0.f};

    // ---- prologue: stage tile 0 + scales 0 ----
    #pragma unroll
    for (int j = 0; j < 4; ++j) {
        GLOAD_LDS16(gA + (size_t)j * 64 * K_DIM, &lds[LS_A(0) + j * 8192 + dst]);
        GLOAD_LDS16(gB + (size_t)j * 64 * K_DIM, &lds[LS_B(0) + j * 8192 + dst]);
    }
    if (wid < 4)
        GLOAD_LDS4(saT + m0 + wid * 64 + lane,
                   &lds[LS_S(0) + wid * 256 + lane * 4]);
    asm volatile("s_waitcnt vmcnt(0)" ::: "memory");
    __builtin_amdgcn_s_barrier();

    for (int i = 0; i < 32; ++i) {
        const int cur = i & 1;
        const int nxt = cur ^ 1;
        const int kbn = (i + 1) & 31;               // wraps: last iter re-stages tile 0 (harmless)
        const int aB = LS_A(cur);
        const int bB = LS_B(cur);
        const int sB = LS_S(cur);
        const float rw = wscale[nbI + i];           // wave-uniform s_load

        #pragma unroll
        for (int ph = 0; ph < 4; ++ph) {
            const int mh = ph >> 1, nh = ph & 1;    // quadrant of wave tile

            // ---- 12x ds_read_b128: 4 A-frags (32B) + 2 B-frags (32B) ----
            i32x8 af[4], bfr[2];
            #pragma unroll
            for (int mi = 0; mi < 4; ++mi) {
                int rb = (wm * 128 + mh * 64 + mi * 16 + lr) * 128;
                int c0 = (lk * 32) ^ fsw;
                i32x4 lo = *(const i32x4*)&lds[aB + rb + c0];
                i32x4 hi = *(const i32x4*)&lds[aB + rb + (c0 ^ 16)];
                af[mi][0] = lo[0]; af[mi][1] = lo[1]; af[mi][2] = lo[2]; af[mi][3] = lo[3];
                af[mi][4] = hi[0]; af[mi][5] = hi[1]; af[mi][6] = hi[2]; af[mi][7] = hi[3];
            }
            #pragma unroll
            for (int ni = 0; ni < 2; ++ni) {
                int rb = (wn * 64 + nh * 32 + ni * 16 + lr) * 128;
                int c0 = (lk * 32) ^ fsw;
                i32x4 lo = *(const i32x4*)&lds[bB + rb + c0];
                i32x4 hi = *(const i32x4*)&lds[bB + rb + (c0 ^ 16)];
                bfr[ni][0] = lo[0]; bfr[ni][1] = lo[1]; bfr[ni][2] = lo[2]; bfr[ni][3] = lo[3];
                bfr[ni][4] = hi[0]; bfr[ni][5] = hi[1]; bfr[ni][6] = hi[2]; bfr[ni][7] = hi[3];
            }

            // ---- front-loaded staging for tile i+1 (A in ph0, B+scales in ph1) ----
            if (ph == 0) {
                #pragma unroll
                for (int j = 0; j < 4; ++j)
                    GLOAD_LDS16(gA + (size_t)kbn * 128 + (size_t)j * 64 * K_DIM,
                                &lds[LS_A(nxt) + j * 8192 + dst]);
            }
            if (ph == 1) {
                #pragma unroll
                for (int j = 0; j < 4; ++j)
                    GLOAD_LDS16(gB + (size_t)kbn * 128 + (size_t)j * 64 * K_DIM,
                                &lds[LS_B(nxt) + j * 8192 + dst]);
                if (wid < 4)
                    GLOAD_LDS4(saT + (size_t)kbn * M + m0 + wid * 64 + lane,
                               &lds[LS_S(nxt) + wid * 256 + lane * 4]);
            }

            __builtin_amdgcn_s_barrier();
            asm volatile("s_waitcnt lgkmcnt(0)" ::: "memory");
            __builtin_amdgcn_sched_barrier(0);

            // ---- 8x mfma_scale K=128 (exact block sums, unit e8m0 scales) ----
            f32x4 bs[4][2];
            __builtin_amdgcn_s_setprio(1);
            #pragma unroll
            for (int mi = 0; mi < 4; ++mi)
                #pragma unroll
                for (int ni = 0; ni < 2; ++ni)
                    bs[mi][ni] = __builtin_amdgcn_mfma_scale_f32_16x16x128_f8f6f4(
                        af[mi], bfr[ni], vzero, 0, 0,
                        0, 0x7F7F7F7F, 0, 0x7F7F7F7F);
            __builtin_amdgcn_s_setprio(0);

            // ---- per-row scale apply for this quadrant ----
            #pragma unroll
            for (int mi = 0; mi < 4; ++mi) {
                f32x4 s4 = *(const f32x4*)&lds[sB + (wm * 128 + mh * 64 + mi * 16 + lk * 4) * 4];
                f32x4 sc = s4 * rw;
                acc[mh * 4 + mi][nh * 2 + 0] += bs[mi][0] * sc;
                acc[mh * 4 + mi][nh * 2 + 1] += bs[mi][1] * sc;
            }

            if (ph == 3) asm volatile("s_waitcnt vmcnt(0)" ::: "memory");
            __builtin_amdgcn_s_barrier();
        }
    }

    // ---- epilogue: C/D layout col=lane&15, row=lk*4+j (verified R1/R3) ----
    #pragma unroll
    for (int q = 0; q < 8; ++q) {
        int mh = q >> 2, mi = q & 3;
        #pragma unroll
        for (int j = 0; j < 4; ++j) {
            int m = m0 + wm * 128 + mh * 64 + mi * 16 + lk * 4 + j;
            float* crow = C + (size_t)m * N_DIM + n0 + wn * 64;
            #pragma unroll
            for (int nc = 0; nc < 4; ++nc) {
                int nh = nc >> 1, ni = nc & 1;
                crow[nh * 32 + ni * 16 + lr] = acc[q][nc][j];
            }
        }
    }
}

extern "C" void kernel_launch(void* const* d_in, const int* in_sizes, int n_in,
                              void* d_out, int out_size, void* d_ws, size_t ws_size,
                              hipStream_t stream) {
    const float* x      = (const float*)d_in[0];
    const float* w      = (const float*)d_in[1];
    const float* wscale = (const float*)d_in[2];
    float* out = (float*)d_out;
    int M = in_sizes[0] / K_DIM;                  // 8192

    // workspace: xq [M*K] | wq [N*K] | saT [32*M]
    uint8_t* xq  = (uint8_t*)d_ws;
    uint8_t* wq  = xq + (size_t)M * K_DIM;
    float*   saT = (float*)(wq + (size_t)N_DIM * K_DIM);

    act_quant_kernel<<<M * NKB / 4, 256, 0, stream>>>(x, xq, saT, M);
    w_quant_kernel<<<((size_t)N_DIM * K_DIM) / 1024, 256, 0, stream>>>(w, wq);

    int nwg = (M / 256) * (N_DIM / 256);
    fp8_gemm_mx2<<<nwg, 512, 0, stream>>>(xq, wq, saT, wscale, out, M);
}

// Round 5
// 262.758 us; speedup vs baseline: 1.5229x; 1.5229x over previous
//
#include <hip/hip_runtime.h>
#include <hip/hip_fp8.h>
#include <stdint.h>

#define K_DIM 4096
#define N_DIM 4096
#define NKB   32     // number of 128-wide K scale blocks

using f32x4 = __attribute__((ext_vector_type(4))) float;
using i32x4 = __attribute__((ext_vector_type(4))) int;
using i32x8 = __attribute__((ext_vector_type(8))) int;

#define GLOAD_LDS16(g, l)                                                      \
    __builtin_amdgcn_global_load_lds(                                          \
        (const __attribute__((address_space(1))) unsigned int*)(g),            \
        (__attribute__((address_space(3))) unsigned int*)(l), 16, 0, 0)
#define GLOAD_LDS4(g, l)                                                       \
    __builtin_amdgcn_global_load_lds(                                          \
        (const __attribute__((address_space(1))) unsigned int*)(g),            \
        (__attribute__((address_space(3))) unsigned int*)(l), 4, 0, 0)

__device__ __forceinline__ uint8_t to_fp8(float v) {
    __hip_fp8_e4m3 q(v);   // OCP e4m3fn, RNE saturating
    return (uint8_t)q.__x;
}

// ---------------- activation quant: one wave per (m, kb); scales TRANSPOSED saT[kb][m] ----------------
__global__ __launch_bounds__(256) void act_quant_kernel(
    const float* __restrict__ x, uint8_t* __restrict__ xq,
    float* __restrict__ saT, int M)
{
    int gw   = blockIdx.x * 4 + (threadIdx.x >> 6);
    int lane = threadIdx.x & 63;
    int m    = gw >> 5;
    int kb   = gw & 31;
    size_t base = (size_t)m * K_DIM + kb * 128 + lane * 2;
    float2 v = *(const float2*)(x + base);
    float amax = fmaxf(fabsf(v.x), fabsf(v.y));
    #pragma unroll
    for (int o = 32; o >= 1; o >>= 1) amax = fmaxf(amax, __shfl_xor(amax, o));
    float s = amax / 448.0f;          // IEEE div, matches jnp exactly
    uchar2 q;
    q.x = to_fp8(v.x / s);
    q.y = to_fp8(v.y / s);
    *(uchar2*)(xq + base) = q;
    if (lane == 0) saT[(size_t)kb * M + m] = s;
}

// ---------------- weight quant ----------------
__global__ __launch_bounds__(256) void w_quant_kernel(
    const float* __restrict__ w, uint8_t* __restrict__ wq)
{
    size_t i = ((size_t)blockIdx.x * 256 + threadIdx.x) * 4;
    float4 v = *(const float4*)(w + i);
    uchar4 q;
    q.x = to_fp8(v.x); q.y = to_fp8(v.y); q.z = to_fp8(v.z); q.w = to_fp8(v.w);
    *(uchar4*)(wq + i) = q;
}

// ---------------- MX fp8 GEMM: 128x128 tile, BK=128, double-buffered 2-phase ----------------
// LDS per buffer: A 16K | B 16K | scales 512B  -> 33280 B; x2 = 66560 B
#define LSA(b) ((b) * 33280)
#define LSB(b) ((b) * 33280 + 16384)
#define LSS(b) ((b) * 33280 + 32768)

__global__ __launch_bounds__(256, 2) void fp8_gemm_mx3(
    const uint8_t* __restrict__ Aq, const uint8_t* __restrict__ Bq,
    const float* __restrict__ saT, const float* __restrict__ wscale,
    float* __restrict__ C, int M)
{
    __shared__ __align__(16) uint8_t lds[66560];

    const int t    = threadIdx.x;
    const int lane = t & 63;
    const int wid  = t >> 6;
    const int lr   = lane & 15;
    const int lk   = lane >> 4;          // 0..3 -> k sub-block of 32
    const int wr   = (wid >> 1) * 64;    // wave row offset
    const int wc   = (wid & 1) * 64;     // wave col offset

    const int nTiles = N_DIM / 128;      // 32
    int mTiles = M / 128;
    int nwg = mTiles * nTiles;           // 2048, %8==0
    int cpx = nwg >> 3;
    int bid = blockIdx.x;
    int swz = (bid & 7) * cpx + (bid >> 3);   // bijective XCD swizzle
    int mT = swz / nTiles, nT = swz % nTiles;
    const int m0 = mT * 128, n0 = nT * 128;

    // staging map (proven R3): thread t -> row srow, phys 16B chunk (t&7);
    // source logical chunk ((t&7)^(srow&7)) => phys_chunk = logical ^ (row&7)
    const int srow = t >> 3;                      // 0..31 per pass
    const int scol = ((t & 7) ^ (srow & 7)) * 16;
    const uint8_t* gA = Aq + (size_t)(m0 + srow) * K_DIM + scol;
    const uint8_t* gB = Bq + (size_t)(n0 + srow) * K_DIM + scol;
    const int ldst = t * 16;

    // fragment read swizzle (row&7)==(lr&7)
    const int fsw = (lr & 7) << 4;
    const int c0  = (lk * 32) ^ fsw;

#define STAGE(buf, kbi) do {                                                   \
    size_t ko_ = (size_t)(kbi) * 128;                                          \
    _Pragma("unroll") for (int j = 0; j < 4; ++j) {                            \
        GLOAD_LDS16(gA + ko_ + (size_t)j * 32 * K_DIM,                         \
                    &lds[LSA(buf) + j * 4096 + ldst]);                         \
        GLOAD_LDS16(gB + ko_ + (size_t)j * 32 * K_DIM,                         \
                    &lds[LSB(buf) + j * 4096 + ldst]);                         \
    }                                                                          \
    if (wid < 2)                                                               \
        GLOAD_LDS4(saT + (size_t)(kbi) * M + m0 + wid * 64 + lane,             \
                   &lds[LSS(buf) + wid * 256 + lane * 4]);                     \
} while (0)

    f32x4 acc[4][4] = {};
    const f32x4 vzero = {0.f, 0.f, 0.f, 0.f};

    // ---- prologue: stage K-block 0 into buf 0 ----
    STAGE(0, 0);
    asm volatile("s_waitcnt vmcnt(0)" ::: "memory");
    __builtin_amdgcn_s_barrier();

    #pragma unroll 2
    for (int kb = 0; kb < NKB; ++kb) {
        const int cur = kb & 1;
        // ---- issue next tile's staging FIRST (overlaps with compute below) ----
        if (kb < NKB - 1) STAGE(cur ^ 1, kb + 1);

        const int aB = LSA(cur), bB = LSB(cur), sB = LSS(cur);
        const float rw = wscale[nT * NKB + kb];   // wave-uniform scalar load

        // ---- fragment loads (2x ds_read_b128 each, swizzled) ----
        i32x8 af[4], bf[4];
        #pragma unroll
        for (int mi = 0; mi < 4; ++mi) {
            int rb = aB + (wr + mi * 16 + lr) * 128;
            i32x4 lo = *(const i32x4*)&lds[rb + c0];
            i32x4 hi = *(const i32x4*)&lds[rb + (c0 ^ 16)];
            af[mi] = __builtin_shufflevector(lo, hi, 0, 1, 2, 3, 4, 5, 6, 7);
        }
        #pragma unroll
        for (int ni = 0; ni < 4; ++ni) {
            int rb = bB + (wc + ni * 16 + lr) * 128;
            i32x4 lo = *(const i32x4*)&lds[rb + c0];
            i32x4 hi = *(const i32x4*)&lds[rb + (c0 ^ 16)];
            bf[ni] = __builtin_shufflevector(lo, hi, 0, 1, 2, 3, 4, 5, 6, 7);
        }

        // ---- 16 exact K=128 block-sum MFMAs + per-row scale accumulate ----
        #pragma unroll
        for (int mi = 0; mi < 4; ++mi) {
            f32x4 s4 = *(const f32x4*)&lds[sB + (wr + mi * 16 + lk * 4) * 4];
            f32x4 sc = s4 * rw;
            f32x4 bs[4];
            #pragma unroll
            for (int ni = 0; ni < 4; ++ni)
                bs[ni] = __builtin_amdgcn_mfma_scale_f32_16x16x128_f8f6f4(
                    af[mi], bf[ni], vzero, 0, 0,
                    0, 0x7F7F7F7F, 0, 0x7F7F7F7F);   // unit e8m0 scales
            #pragma unroll
            for (int ni = 0; ni < 4; ++ni)
                acc[mi][ni] += bs[ni] * sc;
        }

        // ---- single drain + barrier per iteration (T3-min 2-phase) ----
        asm volatile("s_waitcnt vmcnt(0)" ::: "memory");
        __builtin_amdgcn_s_barrier();
    }
#undef STAGE

    // ---- epilogue: C/D layout col=lane&15, row=lk*4+j (verified R1/R3) ----
    #pragma unroll
    for (int mi = 0; mi < 4; ++mi) {
        #pragma unroll
        for (int j = 0; j < 4; ++j) {
            int m = m0 + wr + mi * 16 + lk * 4 + j;
            float* crow = C + (size_t)m * N_DIM + n0 + wc;
            #pragma unroll
            for (int ni = 0; ni < 4; ++ni)
                crow[ni * 16 + lr] = acc[mi][ni][j];
        }
    }
}

extern "C" void kernel_launch(void* const* d_in, const int* in_sizes, int n_in,
                              void* d_out, int out_size, void* d_ws, size_t ws_size,
                              hipStream_t stream) {
    const float* x      = (const float*)d_in[0];
    const float* w      = (const float*)d_in[1];
    const float* wscale = (const float*)d_in[2];
    float* out = (float*)d_out;
    int M = in_sizes[0] / K_DIM;                  // 8192

    // workspace: xq [M*K] | wq [N*K] | saT [32*M]
    uint8_t* xq  = (uint8_t*)d_ws;
    uint8_t* wq  = xq + (size_t)M * K_DIM;
    float*   saT = (float*)(wq + (size_t)N_DIM * K_DIM);

    act_quant_kernel<<<M * NKB / 4, 256, 0, stream>>>(x, xq, saT, M);
    w_quant_kernel<<<((size_t)N_DIM * K_DIM) / 1024, 256, 0, stream>>>(w, wq);

    int nwg = (M / 128) * (N_DIM / 128);
    fp8_gemm_mx3<<<nwg, 256, 0, stream>>>(xq, wq, saT, wscale, out, M);
}

// Round 6
// 234.487 us; speedup vs baseline: 1.7065x; 1.1206x over previous
//
#include <hip/hip_runtime.h>
#include <hip/hip_fp8.h>
#include <stdint.h>

#define K_DIM 4096
#define N_DIM 4096
#define NKB   32     // number of 128-wide K scale blocks

using f32x4 = __attribute__((ext_vector_type(4))) float;
using i32x4 = __attribute__((ext_vector_type(4))) int;
using i32x8 = __attribute__((ext_vector_type(8))) int;

#define GLOAD_LDS16(g, l)                                                      \
    __builtin_amdgcn_global_load_lds(                                          \
        (const __attribute__((address_space(1))) unsigned int*)(g),            \
        (__attribute__((address_space(3))) unsigned int*)(l), 16, 0, 0)
#define GLOAD_LDS4(g, l)                                                       \
    __builtin_amdgcn_global_load_lds(                                          \
        (const __attribute__((address_space(1))) unsigned int*)(g),            \
        (__attribute__((address_space(3))) unsigned int*)(l), 4, 0, 0)

__device__ __forceinline__ uint8_t to_fp8(float v) {
    __hip_fp8_e4m3 q(v);   // OCP e4m3fn, RNE saturating
    return (uint8_t)q.__x;
}

// ---------------- activation quant: one wave per (m, kb); scales TRANSPOSED saT[kb][m] ----------------
__global__ __launch_bounds__(256) void act_quant_kernel(
    const float* __restrict__ x, uint8_t* __restrict__ xq,
    float* __restrict__ saT, int M)
{
    int gw   = blockIdx.x * 4 + (threadIdx.x >> 6);
    int lane = threadIdx.x & 63;
    int m    = gw >> 5;
    int kb   = gw & 31;
    size_t base = (size_t)m * K_DIM + kb * 128 + lane * 2;
    float2 v = *(const float2*)(x + base);
    float amax = fmaxf(fabsf(v.x), fabsf(v.y));
    #pragma unroll
    for (int o = 32; o >= 1; o >>= 1) amax = fmaxf(amax, __shfl_xor(amax, o));
    float s = amax / 448.0f;          // IEEE div, matches jnp exactly
    uchar2 q;
    q.x = to_fp8(v.x / s);
    q.y = to_fp8(v.y / s);
    *(uchar2*)(xq + base) = q;
    if (lane == 0) saT[(size_t)kb * M + m] = s;
}

// ---------------- weight quant ----------------
__global__ __launch_bounds__(256) void w_quant_kernel(
    const float* __restrict__ w, uint8_t* __restrict__ wq)
{
    size_t i = ((size_t)blockIdx.x * 256 + threadIdx.x) * 4;
    float4 v = *(const float4*)(w + i);
    uchar4 q;
    q.x = to_fp8(v.x); q.y = to_fp8(v.y); q.z = to_fp8(v.z); q.w = to_fp8(v.w);
    *(uchar4*)(wq + i) = q;
}

// ---------------- MX fp8 GEMM: 256x256 tile, BK=128, double-buffered 2-phase ----------------
// LDS per buffer: A 32K | B 32K | scales 1K -> 66560 B; x2 = 133120 B (1 block/CU)
#define LSA(b) ((b) * 66560)
#define LSB(b) ((b) * 66560 + 32768)
#define LSS(b) ((b) * 66560 + 65536)

__global__ __launch_bounds__(512, 1) void fp8_gemm_mx4(
    const uint8_t* __restrict__ Aq, const uint8_t* __restrict__ Bq,
    const float* __restrict__ saT, const float* __restrict__ wscale,
    float* __restrict__ C, int M)
{
    __shared__ __align__(16) uint8_t lds[133120];

    const int t    = threadIdx.x;
    const int lane = t & 63;
    const int lr   = lane & 15;
    const int lk   = lane >> 4;          // 0..3 -> k sub-block of 32
    const int wid  = t >> 6;
    const int wm   = wid >> 2;           // 0..1 : wave row half (128 rows)
    const int wn   = wid & 3;            // 0..3 : wave col quarter (64 cols)

    const int gridN = N_DIM / 256;       // 16
    int nwg = (M / 256) * gridN;         // 512, %8==0
    int cpx = nwg >> 3;
    int bid = blockIdx.x;
    int swz = (bid & 7) * cpx + (bid >> 3);   // bijective XCD swizzle
    const int m0 = (swz / gridN) * 256;
    const int n0 = (swz % gridN) * 256;
    const int nbI = ((n0 >> 7) + (wn >> 1)) * NKB;  // wscale row for this wave

    // staging map (proven R3/R5): thread t -> row srow, phys 16B chunk (t&7);
    // source logical chunk ((t&7)^(srow&7)) => phys_chunk = logical ^ (row&7)
    const int srow = t >> 3;                       // 0..63 per pass
    const int scol = ((t & 7) ^ (srow & 7)) * 16;
    const uint8_t* gA = Aq + (size_t)(m0 + srow) * K_DIM + scol;
    const uint8_t* gB = Bq + (size_t)(n0 + srow) * K_DIM + scol;
    const int ldst = t * 16;                       // 8 KB per pass

    // fragment read swizzle: (row&7)==(lr&7)
    const int fsw = (lr & 7) << 4;
    const int c0  = (lk * 32) ^ fsw;

#define STAGE(buf, kbi) do {                                                   \
    size_t ko_ = (size_t)(kbi) * 128;                                          \
    _Pragma("unroll") for (int j = 0; j < 4; ++j) {                            \
        GLOAD_LDS16(gA + ko_ + (size_t)j * 64 * K_DIM,                         \
                    &lds[LSA(buf) + j * 8192 + ldst]);                         \
        GLOAD_LDS16(gB + ko_ + (size_t)j * 64 * K_DIM,                         \
                    &lds[LSB(buf) + j * 8192 + ldst]);                         \
    }                                                                          \
    if (wid < 4)                                                               \
        GLOAD_LDS4(saT + (size_t)(kbi) * M + m0 + wid * 64 + lane,             \
                   &lds[LSS(buf) + wid * 256 + lane * 4]);                     \
} while (0)

    f32x4 acc[8][4] = {};
    const f32x4 vzero = {0.f, 0.f, 0.f, 0.f};

    // ---- prologue: stage K-block 0 into buf 0 ----
    STAGE(0, 0);
    asm volatile("s_waitcnt vmcnt(0)" ::: "memory");
    __builtin_amdgcn_s_barrier();

    #pragma unroll 2
    for (int kb = 0; kb < NKB; ++kb) {
        const int cur = kb & 1;
        // ---- issue next tile's staging FIRST (overlaps compute below) ----
        if (kb < NKB - 1) STAGE(cur ^ 1, kb + 1);

        const int aB = LSA(cur), bB = LSB(cur), sB = LSS(cur);
        const float rw = wscale[nbI + kb];        // wave-uniform scalar load

        // ---- B fragments once (4 x 32B), A per 64-row half (caps VGPR) ----
        i32x8 bf[4];
        #pragma unroll
        for (int ni = 0; ni < 4; ++ni) {
            int rb = bB + (wn * 64 + ni * 16 + lr) * 128;
            i32x4 lo = *(const i32x4*)&lds[rb + c0];
            i32x4 hi = *(const i32x4*)&lds[rb + (c0 ^ 16)];
            bf[ni] = __builtin_shufflevector(lo, hi, 0, 1, 2, 3, 4, 5, 6, 7);
        }
        #pragma unroll
        for (int mh = 0; mh < 2; ++mh) {
            i32x8 af[4];
            #pragma unroll
            for (int mi = 0; mi < 4; ++mi) {
                int rb = aB + (wm * 128 + mh * 64 + mi * 16 + lr) * 128;
                i32x4 lo = *(const i32x4*)&lds[rb + c0];
                i32x4 hi = *(const i32x4*)&lds[rb + (c0 ^ 16)];
                af[mi] = __builtin_shufflevector(lo, hi, 0, 1, 2, 3, 4, 5, 6, 7);
            }
            #pragma unroll
            for (int mi = 0; mi < 4; ++mi) {
                f32x4 s4 = *(const f32x4*)&lds[sB + (wm * 128 + mh * 64 + mi * 16 + lk * 4) * 4];
                f32x4 sc = s4 * rw;
                f32x4 bs[4];
                #pragma unroll
                for (int ni = 0; ni < 4; ++ni)
                    bs[ni] = __builtin_amdgcn_mfma_scale_f32_16x16x128_f8f6f4(
                        af[mi], bf[ni], vzero, 0, 0,
                        0, 0x7F7F7F7F, 0, 0x7F7F7F7F);   // unit e8m0 scales
                #pragma unroll
                for (int ni = 0; ni < 4; ++ni)
                    acc[mh * 4 + mi][ni] += bs[ni] * sc;
            }
        }

        // ---- single drain + barrier per K-block ----
        asm volatile("s_waitcnt vmcnt(0)" ::: "memory");
        __builtin_amdgcn_s_barrier();
    }
#undef STAGE

    // ---- epilogue: C/D layout col=lane&15, row=lk*4+j (verified R1/R3/R4) ----
    #pragma unroll
    for (int q = 0; q < 8; ++q) {
        int mh = q >> 2, mi = q & 3;
        #pragma unroll
        for (int j = 0; j < 4; ++j) {
            int m = m0 + wm * 128 + mh * 64 + mi * 16 + lk * 4 + j;
            float* crow = C + (size_t)m * N_DIM + n0 + wn * 64;
            #pragma unroll
            for (int ni = 0; ni < 4; ++ni)
                crow[ni * 16 + lr] = acc[q][ni][j];
        }
    }
}

extern "C" void kernel_launch(void* const* d_in, const int* in_sizes, int n_in,
                              void* d_out, int out_size, void* d_ws, size_t ws_size,
                              hipStream_t stream) {
    const float* x      = (const float*)d_in[0];
    const float* w      = (const float*)d_in[1];
    const float* wscale = (const float*)d_in[2];
    float* out = (float*)d_out;
    int M = in_sizes[0] / K_DIM;                  // 8192

    // workspace: xq [M*K] | wq [N*K] | saT [32*M]
    uint8_t* xq  = (uint8_t*)d_ws;
    uint8_t* wq  = xq + (size_t)M * K_DIM;
    float*   saT = (float*)(wq + (size_t)N_DIM * K_DIM);

    act_quant_kernel<<<M * NKB / 4, 256, 0, stream>>>(x, xq, saT, M);
    w_quant_kernel<<<((size_t)N_DIM * K_DIM) / 1024, 256, 0, stream>>>(w, wq);

    int nwg = (M / 256) * (N_DIM / 256);
    fp8_gemm_mx4<<<nwg, 512, 0, stream>>>(xq, wq, saT, wscale, out, M);
}